// Round 1
// baseline (5960.241 us; speedup 1.0000x reference)
//
#include <hip/hip_runtime.h>
#include <cstdint>

#define NS 2048      // states S
#define NE 65536     // arcs E
#define ND 2048      // pdfs D
#define NB 32        // batch
#define NT 500       // frames
#define NGROUPS (NS/64)
#define ELLCAP (3*NE)
#define LEAKYF 0.1f

__device__ __forceinline__ float wave_reduce_sum(float v) {
    #pragma unroll
    for (int off = 32; off > 0; off >>= 1)
        v += __shfl_down(v, off, 64);
    return v;
}

__global__ void k_zero(uint32_t* counts, uint32_t* cursor, uint2* arc, float* out) {
    int tid = blockIdx.x * blockDim.x + threadIdx.x;
    int n = blockDim.x * gridDim.x;
    for (int i = tid; i < NS; i += n) { counts[i] = 0u; cursor[i] = 0u; }
    for (int i = tid; i < ELLCAP; i += n) arc[i] = make_uint2(0u, 0u);
    if (tid == 0) out[0] = 0.0f;
}

__global__ void k_count(const int* __restrict__ to_state, uint32_t* counts) {
    int e = blockIdx.x * blockDim.x + threadIdx.x;
    if (e < NE) atomicAdd(&counts[to_state[e]], 1u);
}

// widths[g] = max arc-count among the 64 states of group g; gbase = exclusive scan of 64*width
__global__ void k_widths(const uint32_t* __restrict__ counts, uint32_t* widths, uint32_t* gbase) {
    int g = threadIdx.x;
    if (g < NGROUPS) {
        uint32_t w = 0u;
        for (int i = 0; i < 64; ++i) w = max(w, counts[g*64 + i]);
        widths[g] = w;
    }
    __syncthreads();
    if (threadIdx.x == 0) {
        uint32_t acc = 0u;
        for (int g2 = 0; g2 < NGROUPS; ++g2) {
            gbase[g2] = acc;
            acc += widths[g2] * 64u;
        }
        gbase[NGROUPS] = acc;  // total (fits in ELLCAP for random to_state)
    }
}

__global__ void k_scatter(const int* __restrict__ from_state, const int* __restrict__ to_state,
                          const int* __restrict__ pdf_ids, const float* __restrict__ log_w,
                          const uint32_t* __restrict__ gbase, uint32_t* cursor, uint2* arc) {
    int e = blockIdx.x * blockDim.x + threadIdx.x;
    if (e >= NE) return;
    int s = to_state[e];
    int g = s >> 6;
    uint32_t slot = atomicAdd(&cursor[s], 1u);
    uint32_t pos = gbase[g] + slot * 64u + (uint32_t)(s & 63);
    uint32_t meta = (uint32_t)from_state[e] | ((uint32_t)pdf_ids[e] << 16);
    float w = __expf(log_w[e]);
    arc[pos] = make_uint2(meta, __float_as_uint(w));
}

// One workgroup per batch element. Whole T-loop in-kernel; alpha kept in LDS in
// LINEAR domain, renormalized by total mass each step (C accumulates log-normalizer).
__global__ __launch_bounds__(1024) void k_fwd(
    const float* __restrict__ x, const float* __restrict__ log_init,
    const float* __restrict__ log_final,
    const uint2* __restrict__ arc, const uint32_t* __restrict__ widths,
    const uint32_t* __restrict__ gbase, float* out)
{
    __shared__ float bufA[NS], bufB[NS], Xs[ND], initL[NS];
    __shared__ float red[16];
    __shared__ uint32_t wbase[NGROUPS], wwid[NGROUPS];

    const int tid  = threadIdx.x;
    const int b    = blockIdx.x;
    const int lane = tid & 63;
    const int wid  = tid >> 6;

    for (int s2 = tid; s2 < NS; s2 += 1024) {
        float ie = __expf(log_init[s2]);
        initL[s2] = ie;
        bufA[s2]  = ie;        // alpha0 = log_init  ->  a = exp(log_init), C = 0
    }
    if (tid < NGROUPS) { wbase[tid] = gbase[tid]; wwid[tid] = widths[tid]; }
    __syncthreads();

    float C = 0.0f;
    const float* xrow = x + (size_t)b * NT * ND;

    for (int t = 0; t < NT; ++t) {
        float* cur = (t & 1) ? bufB : bufA;
        float* nxt = (t & 1) ? bufA : bufB;

        // stage exp(x[b,t,:]) into LDS (coalesced, 2 elems/thread)
        {
            float v0 = xrow[t*ND + tid];
            float v1 = xrow[t*ND + tid + 1024];
            Xs[tid]        = __expf(v0);
            Xs[tid + 1024] = __expf(v1);
        }

        // T = sum_s a[s]  (block reduction, fixed order)
        float p = cur[tid] + cur[tid + 1024];
        p = wave_reduce_sum(p);
        if (lane == 0) red[wid] = p;
        __syncthreads();                       // red + Xs visible
        float Tsum = 0.0f;
        #pragma unroll
        for (int i = 0; i < 16; ++i) Tsum += red[i];
        float invT = 1.0f / Tsum;
        C += __logf(Tsum);

        // leaky-HMM + normalize, in place:  e2 = a/T + LEAKY*init
        cur[tid]        = cur[tid]        * invT + LEAKYF * initL[tid];
        cur[tid + 1024] = cur[tid + 1024] * invT + LEAKYF * initL[tid + 1024];
        __syncthreads();                       // e2 complete

        // arc pass: wave 'wid' owns groups 2*wid, 2*wid+1; lane owns state g*64+lane.
        // ELL layout: arc slot i of this state at arc[base + i*64 + lane] (coalesced).
        #pragma unroll
        for (int gg = 0; gg < 2; ++gg) {
            int g = wid * 2 + gg;
            int s = g * 64 + lane;
            const uint2* ap = arc + wbase[g] + lane;
            int wd = (int)wwid[g];
            float acc0 = 0.0f, acc1 = 0.0f;
            int i = 0;
            for (; i + 2 <= wd; i += 2) {
                uint2 a0 = ap[(size_t)i * 64];
                uint2 a1 = ap[(size_t)(i + 1) * 64];
                acc0 += cur[a0.x & 0xFFFFu] * __uint_as_float(a0.y) * Xs[a0.x >> 16];
                acc1 += cur[a1.x & 0xFFFFu] * __uint_as_float(a1.y) * Xs[a1.x >> 16];
            }
            if (i < wd) {
                uint2 a0 = ap[(size_t)i * 64];
                acc0 += cur[a0.x & 0xFFFFu] * __uint_as_float(a0.y) * Xs[a0.x >> 16];
            }
            nxt[s] = acc0 + acc1;   // padding slots have w=0 -> contribute 0
        }
        __syncthreads();                       // nxt complete before next step
    }

    // objf = log(sum_s a_T[s]*exp(log_final[s])) + C ; out = -sum_b objf
    float* fin = (NT & 1) ? bufB : bufA;
    float p = fin[tid] * __expf(log_final[tid])
            + fin[tid + 1024] * __expf(log_final[tid + 1024]);
    p = wave_reduce_sum(p);
    if (lane == 0) red[wid] = p;
    __syncthreads();
    if (tid == 0) {
        float tot = 0.0f;
        #pragma unroll
        for (int i = 0; i < 16; ++i) tot += red[i];
        atomicAdd(out, -(__logf(tot) + C));
    }
}

extern "C" void kernel_launch(void* const* d_in, const int* in_sizes, int n_in,
                              void* d_out, int out_size, void* d_ws, size_t ws_size,
                              hipStream_t stream) {
    const float* x         = (const float*)d_in[0];
    const float* log_w     = (const float*)d_in[1];
    const float* log_init  = (const float*)d_in[2];
    const float* log_final = (const float*)d_in[3];
    const int*   from_st   = (const int*)d_in[4];
    const int*   to_st     = (const int*)d_in[5];
    const int*   pdf_ids   = (const int*)d_in[6];
    float* out = (float*)d_out;

    uint8_t* ws = (uint8_t*)d_ws;
    uint32_t* counts = (uint32_t*)ws;          // 2048
    uint32_t* cursor = counts + NS;            // 2048
    uint32_t* widths = cursor + NS;            // 32
    uint32_t* gbase  = widths + NGROUPS;       // 33
    uint2*    arc    = (uint2*)(ws + 32768);   // ELLCAP entries (1.5 MB)

    k_zero   <<<256, 256, 0, stream>>>(counts, cursor, arc, out);
    k_count  <<<NE/256, 256, 0, stream>>>(to_st, counts);
    k_widths <<<1, 64, 0, stream>>>(counts, widths, gbase);
    k_scatter<<<NE/256, 256, 0, stream>>>(from_st, to_st, pdf_ids, log_w, gbase, cursor, arc);
    k_fwd    <<<NB, 1024, 0, stream>>>(x, log_init, log_final, arc, widths, gbase, out);
}